// Round 16
// baseline (106.292 us; speedup 1.0000x reference)
//
#include <hip/hip_runtime.h>
#include <hip/hip_bf16.h>
#include <hip/hip_fp16.h>

#define EPSF 1e-5f

typedef __attribute__((ext_vector_type(8))) _Float16 half8;
typedef __attribute__((ext_vector_type(2))) _Float16 half2v;
typedef __attribute__((ext_vector_type(4))) float f32x4;

__device__ __forceinline__ int seg_of(int i, int o0, int o1, int o2) {
    return (i >= o0) + (i >= o1) + (i >= o2);
}

__device__ __forceinline__ unsigned short f2h(float f) {
    _Float16 h = (_Float16)f;
    unsigned short s; __builtin_memcpy(&s, &h, 2);
    return s;
}
// v_cvt_pkrtz_f16_f32: 1 instruction packs two floats to half2
__device__ __forceinline__ unsigned int pack2h(float a, float b) {
    auto h = __builtin_amdgcn_cvt_pkrtz(a, b);   // __fp16 ext_vector(2)
    unsigned int u; __builtin_memcpy(&u, &h, 4);
    return u;
}
__device__ __forceinline__ float hlo(unsigned int u) {
    unsigned short s = (unsigned short)u;
    _Float16 h; __builtin_memcpy(&h, &s, 2);
    return (float)h;
}
__device__ __forceinline__ float hhi(unsigned int u) {
    unsigned short s = (unsigned short)(u >> 16);
    _Float16 h; __builtin_memcpy(&h, &s, 2);
    return (float)h;
}
__device__ __forceinline__ half2v u2h2(unsigned int u) {
    half2v h; __builtin_memcpy(&h, &u, 4);
    return h;
}
__device__ __forceinline__ unsigned int h22u(half2v h) {
    unsigned int u; __builtin_memcpy(&u, &h, 4);
    return u;
}

// stage 16 rows x 64 f16 from global (row-major 64) into LDS (stride 72)
__device__ __forceinline__ void stage_rows_h(const unsigned short* __restrict__ src,
                                             unsigned short* dst, int l) {
    int row = l >> 2, cq = (l & 3) * 16;
    const half8* s = (const half8*)(src + (size_t)row*64 + cq);
    half8* d0 = (half8*)(dst + row*72 + cq);
    d0[0] = s[0];
    d0[1] = s[1];
}

// stage 16 rows x 64 f32 from global into f16 LDS (stride 72)
__device__ __forceinline__ void stage_rows_f32(const float* __restrict__ src,
                                               unsigned short* dst, int l) {
    int row = l >> 2, cq = (l & 3) * 16;
    const float4* s = (const float4*)(src + (size_t)row*64 + cq);
    unsigned int* d = (unsigned int*)(dst + row*72 + cq);
    #pragma unroll
    for (int i = 0; i < 4; ++i) {
        float4 f = s[i];
        d[i*2]   = pack2h(f.x, f.y);
        d[i*2+1] = pack2h(f.z, f.w);
    }
}

// ---------------------------------------------------------------------------
// K0: fold BNs; build all f16 MFMA B-fragments + folded biases; zero seg_max.
// ---------------------------------------------------------------------------
__global__ __launch_bounds__(256) void k_prep(
    const float* __restrict__ pe_W1, const float* __restrict__ pe_b1, const float* __restrict__ pe_bn,
    const float* __restrict__ pe_W2, const float* __restrict__ pe_b2,
    const float* __restrict__ we_W1, const float* __restrict__ we_b1, const float* __restrict__ we_bn,
    const float* __restrict__ we_W2,
    const float* __restrict__ cg_W1, const float* __restrict__ cg_b1, const float* __restrict__ cg_bn,
    const float* __restrict__ cg_W2,
    const float* __restrict__ Wq, const float* __restrict__ bq, const float* __restrict__ bnq,
    const float* __restrict__ Wk, const float* __restrict__ bk, const float* __restrict__ bnk,
    const float* __restrict__ Wv,
    float* __restrict__ peb1f, float* __restrict__ cvecg, float* __restrict__ cgb1f,
    float* __restrict__ biasqF, float* __restrict__ biaskF, float* __restrict__ cgW1cF,
    float* __restrict__ segm,
    unsigned short* __restrict__ WqF, unsigned short* __restrict__ WkF, unsigned short* __restrict__ WvF,
    unsigned short* __restrict__ weW1F, unsigned short* __restrict__ cgW1aF,
    unsigned short* __restrict__ cgW1bF, unsigned short* __restrict__ cgW2F,
    unsigned short* __restrict__ W1frag, unsigned short* __restrict__ Wcfrag,
    unsigned short* __restrict__ W2frag)
{
    int t = threadIdx.x;
    __shared__ float sc1[64], csc[64], sqv[64], skv[64], wsc[8], wsh[8];
    __shared__ float sWe[64][8], sWb[8], sWc[64][8];
    segm[t] = 0.f;
    if (t < 64) {
        float g = pe_bn[t], b = pe_bn[64+t], m = pe_bn[128+t], v = pe_bn[192+t];
        float s = g / sqrtf(v + EPSF);
        sc1[t] = s; peb1f[t] = pe_b1[t]*s + (b - m*s);
        g = cg_bn[t]; b = cg_bn[64+t]; m = cg_bn[128+t]; v = cg_bn[192+t];
        s = g / sqrtf(v + EPSF);
        csc[t] = s; cgb1f[t] = cg_b1[t]*s + (b - m*s);
        g = bnq[t]; b = bnq[64+t]; m = bnq[128+t]; v = bnq[192+t];
        s = g / sqrtf(v + EPSF);
        sqv[t] = s; biasqF[t] = bq[t]*s + (b - m*s);
        g = bnk[t]; b = bnk[64+t]; m = bnk[128+t]; v = bnk[192+t];
        s = g / sqrtf(v + EPSF);
        skv[t] = s; biaskF[t] = bk[t]*s + (b - m*s);
    }
    if (t < 8) {
        float g = we_bn[t], b = we_bn[8+t], m = we_bn[16+t], v = we_bn[24+t];
        float s = g / sqrtf(v + EPSF);
        wsc[t] = s; wsh[t] = b - m*s;
    }
    __syncthreads();
    for (int u = t; u < 512; u += 256) { int g = u & 7; sWe[u >> 3][g] = we_W1[u] * wsc[g]; }
    if (t < 8) sWb[t] = we_b1[t] * wsc[t] + wsh[t];
    __syncthreads();
    for (int u = t; u < 512; u += 256) {
        int h = u >> 3, g = u & 7;
        float a = 0.f;
        for (int c = 0; c < 64; ++c) a += pe_W2[h*64 + c] * sWe[c][g];
        sWc[h][g] = a;
    }
    if (t < 8) {
        float a = sWb[t];
        for (int c = 0; c < 64; ++c) a += pe_b2[c] * sWe[c][t];
        cvecg[t] = a;
    }
    __syncthreads();
    // 64x64 frags (8 tiles x 512)
    for (int u = t; u < 4096; u += 256) {
        int tile = u >> 9, l = (u >> 3) & 63, j = u & 7;
        int col = (tile >> 1)*16 + (l & 15);
        int kk  = (tile & 1)*32 + (l >> 4)*8 + j;
        WqF[u]    = f2h(Wq[kk*64 + col] * sqv[col]);
        WkF[u]    = f2h(Wk[kk*64 + col] * skv[col]);
        WvF[u]    = f2h(Wv[kk*64 + col]);
        cgW1aF[u] = f2h(cg_W1[kk*64 + col] * csc[col]);
        cgW1bF[u] = f2h(cg_W1[(64 + kk)*64 + col] * csc[col]);
    }
    // 64->8/8->8 frags (2 tiles, cols padded to 16)
    for (int u = t; u < 1024; u += 256) {
        int tile = u >> 9, l = (u >> 3) & 63, j = u & 7;
        int col = l & 15;
        int kk  = tile*32 + (l >> 4)*8 + j;
        weW1F[u] = (col < 8) ? f2h(sWe[kk][col]) : 0;
        cgW2F[u] = (col < 8) ? f2h(cg_W2[kk*8 + col]) : 0;
    }
    // cgW1cF: rows 128..191 of cg_W1, BN-folded, f32
    for (int u = t; u < 4096; u += 256) {
        int k = u >> 6, c = u & 63;
        cgW1cF[u] = cg_W1[(128 + k)*64 + c] * csc[c];
    }
    // k_main frags
    {
        int ct = t >> 6, l = t & 63;
        int col = 16*ct + (l & 15), kg = l >> 4;
        #pragma unroll
        for (int j = 0; j < 8; ++j) {
            int k = kg*8 + j;
            float v = (k < 28) ? pe_W1[k*64 + col] * sc1[col] : 0.f;
            W1frag[ct*512 + l*8 + j] = f2h(v);
        }
    }
    if (t < 128) {
        int kg = t >> 6, l = t & 63, g = l & 15;
        #pragma unroll
        for (int j = 0; j < 8; ++j) {
            int k = kg*32 + (l >> 4)*8 + j;
            float v = (g < 8) ? sWc[k][g] : 0.f;
            Wcfrag[kg*512 + l*8 + j] = f2h(v);
        }
    }
    if (t < 64) {
        int l = t, g = l & 15;
        #pragma unroll
        for (int j = 0; j < 8; ++j) {
            float v = (l < 16 && g < 8) ? we_W2[j*8 + g] : 0.f;
            W2frag[l*8 + j] = f2h(v);
        }
    }
}

// ---------------------------------------------------------------------------
// K1: MFMA q/k/v (f16). Block = 4 waves x 16 rows, wave-private LDS.
// ---------------------------------------------------------------------------
__global__ __launch_bounds__(256) void k_qkv(
    const float* __restrict__ feat, const int* __restrict__ offs,
    const unsigned short* __restrict__ WqF, const unsigned short* __restrict__ WkF,
    const unsigned short* __restrict__ WvF, const unsigned short* __restrict__ weW1F,
    const float* __restrict__ biasqF, const float* __restrict__ biaskF,
    const float* __restrict__ bv,
    unsigned short* __restrict__ v_hf, unsigned short* __restrict__ q_hf,
    float* __restrict__ kw, float* __restrict__ qw, float* __restrict__ seg_max)
{
    __shared__ unsigned short sF[4][16*72];
    __shared__ unsigned short sQ[4][16*72];
    __shared__ unsigned short sK[4][16*72];
    __shared__ float sSeg[64];

    int t = threadIdx.x, w = t >> 6, l = t & 63;
    int lc = l & 15, lg = l >> 4;
    int rblk = blockIdx.x * 64;
    int r0 = rblk + w * 16;
    int o0 = offs[0], o1 = offs[1], o2 = offs[2];
    bool fast = seg_of(rblk, o0,o1,o2) == seg_of(rblk + 63, o0,o1,o2);

    if (t < 64) sSeg[t] = 0.f;
    __syncthreads();

    stage_rows_f32(feat + (size_t)r0*64, sF[w], l);
    half8 a0 = *(const half8*)(sF[w] + lc*72 + lg*8);
    half8 a1 = *(const half8*)(sF[w] + lc*72 + 32 + lg*8);

    float bqc[4], bkc[4], bvc[4];
    #pragma unroll
    for (int ct = 0; ct < 4; ++ct) {
        bqc[ct] = biasqF[ct*16 + lc];
        bkc[ct] = biaskF[ct*16 + lc];
        bvc[ct] = bv[ct*16 + lc];
    }

    // ---- q ----
    #pragma unroll
    for (int ct = 0; ct < 4; ++ct) {
        f32x4 z = {0.f,0.f,0.f,0.f};
        half8 b0 = *(const half8*)(WqF + (ct*2+0)*512 + l*8);
        half8 b1 = *(const half8*)(WqF + (ct*2+1)*512 + l*8);
        f32x4 c = __builtin_amdgcn_mfma_f32_16x16x32_f16(a0, b0, z, 0,0,0);
        c = __builtin_amdgcn_mfma_f32_16x16x32_f16(a1, b1, c, 0,0,0);
        float cmax = 0.f;
        #pragma unroll
        for (int reg = 0; reg < 4; ++reg) {
            float qv = fmaxf(c[reg] + bqc[ct], 0.f);
            sQ[w][(lg*4 + reg)*72 + ct*16 + lc] = f2h(qv);
            if (fast) cmax = fmaxf(cmax, qv);
            else atomicMax((unsigned int*)&seg_max[seg_of(r0 + lg*4 + reg,o0,o1,o2)*64 + ct*16 + lc],
                           __float_as_uint(qv));
        }
        if (fast) {
            cmax = fmaxf(cmax, __shfl_xor(cmax, 16));
            cmax = fmaxf(cmax, __shfl_xor(cmax, 32));
            if (lg == 0)
                atomicMax((unsigned int*)&sSeg[ct*16 + lc], __float_as_uint(cmax));
        }
    }
    // ---- seg-max combine early ----
    __syncthreads();
    if (fast && t < 64)
        atomicMax((unsigned int*)&seg_max[seg_of(rblk,o0,o1,o2)*64 + t],
                  __float_as_uint(sSeg[t]));

    // ---- k ----
    #pragma unroll
    for (int ct = 0; ct < 4; ++ct) {
        f32x4 z = {0.f,0.f,0.f,0.f};
        half8 b0 = *(const half8*)(WkF + (ct*2+0)*512 + l*8);
        half8 b1 = *(const half8*)(WkF + (ct*2+1)*512 + l*8);
        f32x4 c = __builtin_amdgcn_mfma_f32_16x16x32_f16(a0, b0, z, 0,0,0);
        c = __builtin_amdgcn_mfma_f32_16x16x32_f16(a1, b1, c, 0,0,0);
        #pragma unroll
        for (int reg = 0; reg < 4; ++reg)
            sK[w][(lg*4 + reg)*72 + ct*16 + lc] = f2h(fmaxf(c[reg] + bkc[ct], 0.f));
    }
    // ---- v (staged f16 into sF, which is dead now) ----
    #pragma unroll
    for (int ct = 0; ct < 4; ++ct) {
        f32x4 z = {0.f,0.f,0.f,0.f};
        half8 b0 = *(const half8*)(WvF + (ct*2+0)*512 + l*8);
        half8 b1 = *(const half8*)(WvF + (ct*2+1)*512 + l*8);
        f32x4 c = __builtin_amdgcn_mfma_f32_16x16x32_f16(a0, b0, z, 0,0,0);
        c = __builtin_amdgcn_mfma_f32_16x16x32_f16(a1, b1, c, 0,0,0);
        #pragma unroll
        for (int reg = 0; reg < 4; ++reg)
            sF[w][(lg*4 + reg)*72 + ct*16 + lc] = f2h(c[reg] + bvc[ct]);
    }
    // ---- kw / qw via MFMA (K=64 -> 8 cols) ----
    {
        half8 wb0 = *(const half8*)(weW1F + l*8);
        half8 wb1 = *(const half8*)(weW1F + 512 + l*8);
        half8 aq0 = *(const half8*)(sQ[w] + lc*72 + lg*8);
        half8 aq1 = *(const half8*)(sQ[w] + lc*72 + 32 + lg*8);
        half8 ak0 = *(const half8*)(sK[w] + lc*72 + lg*8);
        half8 ak1 = *(const half8*)(sK[w] + lc*72 + 32 + lg*8);
        f32x4 z = {0.f,0.f,0.f,0.f};
        f32x4 cq = __builtin_amdgcn_mfma_f32_16x16x32_f16(aq0, wb0, z, 0,0,0);
        cq = __builtin_amdgcn_mfma_f32_16x16x32_f16(aq1, wb1, cq, 0,0,0);
        f32x4 ck = __builtin_amdgcn_mfma_f32_16x16x32_f16(ak0, wb0, z, 0,0,0);
        ck = __builtin_amdgcn_mfma_f32_16x16x32_f16(ak1, wb1, ck, 0,0,0);
        if (lc < 8) {
            #pragma unroll
            for (int reg = 0; reg < 4; ++reg) {
                qw[(size_t)(r0 + lg*4 + reg)*8 + lc] = cq[reg];
                kw[(size_t)(r0 + lg*4 + reg)*8 + lc] = ck[reg];
            }
        }
    }
    // ---- q_hf / v_hf global writes ----
    #pragma unroll
    for (int rep = 0; rep < 2; ++rep) {
        int row = (l >> 3) + rep*8;
        int ch = (l & 7) * 8;
        half8 vq = *(const half8*)(sQ[w] + row*72 + ch);
        *(half8*)(q_hf + (size_t)(r0 + row)*64 + ch) = vq;
        half8 vv = *(const half8*)(sF[w] + row*72 + ch);
        *(half8*)(v_hf + (size_t)(r0 + row)*64 + ch) = vv;
    }
}

// ---------------------------------------------------------------------------
// K3 (fused): gate (phase A, incl. per-block gseg2) + PE/softmax/einsum.
// R10 structure (xe once into block-wide sA1) + f16 everywhere.
// LDS 38.6 KB -> 4 blocks/CU.
// ---------------------------------------------------------------------------
__global__ __launch_bounds__(256, 4) void k_main(
    const float* __restrict__ coord, const int* __restrict__ ridx,
    const unsigned short* __restrict__ v_hf, const unsigned short* __restrict__ q_hf,
    const float* __restrict__ kw, const float* __restrict__ qw,
    const float* __restrict__ peb1f, const float* __restrict__ cvecg,
    const float* __restrict__ we_b2, const float* __restrict__ cg_b2,
    const float* __restrict__ seg_max, const float* __restrict__ cgW1cF,
    const float* __restrict__ cgb1f, const int* __restrict__ offs,
    const unsigned short* __restrict__ W1frag, const unsigned short* __restrict__ Wcfrag,
    const unsigned short* __restrict__ W2frag,
    const unsigned short* __restrict__ cgW1aF, const unsigned short* __restrict__ cgW1bF,
    const unsigned short* __restrict__ cgW2F,
    float* __restrict__ out)
{
    __shared__ __align__(16) unsigned short sA1[256*40];   // 20480 B xe rows (block-wide)
    __shared__ __align__(16) unsigned short sA2[4][16*72]; // 9216 B per-wave H1
    __shared__ __align__(16) unsigned short sU[3584];      // 7168 B union
    __shared__ float sGate[16][9];                         // 576 B
    __shared__ float sGseg[4][64];                         // 1024 B
    __shared__ int sIds[256];                              // 1024 B

    int t = threadIdx.x, w = t >> 6, l = t & 63;
    int lc = l & 15, lg = l >> 4;
    int n0 = blockIdx.x * 16;
    int o0 = offs[0], o1 = offs[1], o2 = offs[2];

    unsigned short* sQg = sU;
    unsigned short* sN  = sU + 1152;
    unsigned short* sHg = sU + 2304;
    unsigned short* sAh2w  = sU + w*128;
    unsigned short* sAttnB = sU + 512;

    // ---- step 1: ids + xe row computed ONCE (pkrtz packing) + gseg2 ----
    int id = ridx[(size_t)n0*16 + t];
    sIds[t] = id;
    int ids = max(id, 0);
    int nself = n0 + (t >> 4);
    {
        float cx = coord[nself*3], cy = coord[nself*3+1], cz = coord[nself*3+2];
        float dx = coord[ids*3]   - cx;
        float dy = coord[ids*3+1] - cy;
        float dz = coord[ids*3+2] - cz;
        float dist = sqrtf(dx*dx + dy*dy + dz*dz);
        unsigned int* row = (unsigned int*)sA1 + t*20;
        row[0] = pack2h(dx, dy);
        row[1] = pack2h(dz, dist);
        float sx, cx2, sy, cy2, sz, cz2;
        __sincosf(dx * 3.14159265358979f, &sx, &cx2);
        __sincosf(dy * 3.14159265358979f, &sy, &cy2);
        __sincosf(dz * 3.14159265358979f, &sz, &cz2);
        row[2]  = pack2h(sx, sy);
        row[3]  = pack2h(cx2, cy2);
        row[10] = pack2h(sz, cz2);
        #pragma unroll
        for (int fi = 1; fi < 4; ++fi) {
            float nsx = 2.f*sx*cx2, ncx = fmaf(-2.f*sx, sx, 1.f);
            float nsy = 2.f*sy*cy2, ncy = fmaf(-2.f*sy, sy, 1.f);
            float nsz = 2.f*sz*cz2, ncz = fmaf(-2.f*sz, sz, 1.f);
            row[2 + 2*fi] = pack2h(nsx, nsy);
            row[3 + 2*fi] = pack2h(ncx, ncy);
            row[10 + fi]  = pack2h(nsz, ncz);
            sx = nsx; cx2 = ncx; sy = nsy; cy2 = ncy; sz = nsz; cz2 = ncz;
        }
        row[14] = 0u; row[15] = 0u;
    }
    if (t < 64) stage_rows_h(q_hf + (size_t)n0*64, sQg, t);
    // gseg2 per block: thread (s=w, c=l)
    {
        float a = cgb1f[l];
        #pragma unroll 8
        for (int j = 0; j < 64; ++j)
            a += seg_max[w*64 + j] * cgW1cF[j*64 + l];
        sGseg[w][l] = a;
    }
    __syncthreads();   // sIds + sQg + sGseg + sA1 ready

    // ---- step 2: neighbor-max gather in packed f16 (v_pk_max_f16) ----
    {
        int p = t >> 4, s = t & 15;
        const int* ip = &sIds[p*16];
        half2v m0 = (half2v)0, m1 = (half2v)0;
        #pragma unroll
        for (int kb = 0; kb < 16; kb += 4) {
            uint2 u[4];
            #pragma unroll
            for (int j = 0; j < 4; ++j) {
                int idn = max(ip[kb + j], 0);
                u[j] = *(const uint2*)(q_hf + (size_t)idn*64 + s*4);
            }
            #pragma unroll
            for (int j = 0; j < 4; ++j) {
                m0 = __builtin_elementwise_max(m0, u2h2(u[j].x));
                m1 = __builtin_elementwise_max(m1, u2h2(u[j].y));
            }
        }
        unsigned int* d = (unsigned int*)(sN + p*72 + s*4);
        d[0] = h22u(m0);
        d[1] = h22u(m1);
    }
    __syncthreads();   // sN ready

    // ---- step 3: gate H1 (wave w owns output col-tile ct=w) ----
    {
        half8 a0 = *(const half8*)(sQg + lc*72 + lg*8);
        half8 a1 = *(const half8*)(sQg + lc*72 + 32 + lg*8);
        half8 nv0 = *(const half8*)(sN + lc*72 + lg*8);
        half8 nv1 = *(const half8*)(sN + lc*72 + 32 + lg*8);
        f32x4 c4;
        #pragma unroll
        for (int reg = 0; reg < 4; ++reg)
            c4[reg] = sGseg[seg_of(n0 + lg*4 + reg, o0, o1, o2)][w*16 + lc];
        half8 b0 = *(const half8*)(cgW1aF + (w*2+0)*512 + l*8);
        half8 b1 = *(const half8*)(cgW1aF + (w*2+1)*512 + l*8);
        c4 = __builtin_amdgcn_mfma_f32_16x16x32_f16(a0, b0, c4, 0,0,0);
        c4 = __builtin_amdgcn_mfma_f32_16x16x32_f16(a1, b1, c4, 0,0,0);
        half8 b2 = *(const half8*)(cgW1bF + (w*2+0)*512 + l*8);
        half8 b3 = *(const half8*)(cgW1bF + (w*2+1)*512 + l*8);
        c4 = __builtin_amdgcn_mfma_f32_16x16x32_f16(nv0, b2, c4, 0,0,0);
        c4 = __builtin_amdgcn_mfma_f32_16x16x32_f16(nv1, b3, c4, 0,0,0);
        #pragma unroll
        for (int reg = 0; reg < 4; ++reg)
            sHg[(lg*4 + reg)*72 + w*16 + lc] = f2h(fmaxf(c4[reg], 0.f));
    }
    __syncthreads();   // sHg ready

    // ---- step 4: final gate MFMA (wave 0 only) ----
    if (w == 0) {
        half8 ah0 = *(const half8*)(sHg + lc*72 + lg*8);
        half8 ah1 = *(const half8*)(sHg + lc*72 + 32 + lg*8);
        half8 w0f = *(const half8*)(cgW2F + l*8);
        half8 w1f = *(const half8*)(cgW2F + 512 + l*8);
        float bg = cg_b2[lc & 7];
        f32x4 cg;
        #pragma unroll
        for (int reg = 0; reg < 4; ++reg) cg[reg] = bg;
        cg = __builtin_amdgcn_mfma_f32_16x16x32_f16(ah0, w0f, cg, 0,0,0);
        cg = __builtin_amdgcn_mfma_f32_16x16x32_f16(ah1, w1f, cg, 0,0,0);
        if (lc < 8) {
            #pragma unroll
            for (int reg = 0; reg < 4; ++reg)
                sGate[lg*4 + reg][lc] = 1.f / (1.f + __expf(-cg[reg]));
        }
    }
    __syncthreads();   // sGate ready; phase-A scratch dead -> reuse

    // ---- phase B: per-wave PE pipeline ----
    int g7 = lc & 7;
    half8 bW1[4], bWc[2], bW2;
    #pragma unroll
    for (int ct = 0; ct < 4; ++ct) bW1[ct] = *(const half8*)(W1frag + ct*512 + l*8);
    bWc[0] = *(const half8*)(Wcfrag + l*8);
    bWc[1] = *(const half8*)(Wcfrag + 512 + l*8);
    bW2 = *(const half8*)(W2frag + l*8);

    float bias1[4];
    #pragma unroll
    for (int ct = 0; ct < 4; ++ct) bias1[ct] = peb1f[16*ct + lc];
    float cvec_g = cvecg[g7];
    float bias3 = we_b2[g7];

    #pragma unroll
    for (int rt = 0; rt < 4; ++rt) {
        int n = n0 + w*4 + rt;
        half8 a1 = *(const half8*)(sA1 + (w*64 + rt*16 + lc)*40 + lg*8);
        f32x4 c1[4];
        #pragma unroll
        for (int ct = 0; ct < 4; ++ct) {
            f32x4 z = {0.f, 0.f, 0.f, 0.f};
            c1[ct] = __builtin_amdgcn_mfma_f32_16x16x32_f16(a1, bW1[ct], z, 0, 0, 0);
        }
        #pragma unroll
        for (int ct = 0; ct < 4; ++ct) {
            #pragma unroll
            for (int reg = 0; reg < 4; ++reg) {
                float h1 = fmaxf(c1[ct][reg] + bias1[ct], 0.f);
                sA2[w][(lg*4 + reg)*72 + 16*ct + lc] = f2h(h1);
            }
        }
        int ids_r[4];
        #pragma unroll
        for (int reg = 0; reg < 4; ++reg) ids_r[reg] = sIds[w*64 + rt*16 + lg*4 + reg];
        float qwv = qw[(size_t)n*8 + g7];
        f32x4 c2;
        #pragma unroll
        for (int reg = 0; reg < 4; ++reg)
            c2[reg] = kw[(size_t)max(ids_r[reg],0)*8 + g7] - qwv + cvec_g;
        half8 a20 = *(const half8*)(sA2[w] + lc*72 + lg*8);
        half8 a21 = *(const half8*)(sA2[w] + lc*72 + 32 + lg*8);
        c2 = __builtin_amdgcn_mfma_f32_16x16x32_f16(a20, bWc[0], c2, 0, 0, 0);
        c2 = __builtin_amdgcn_mfma_f32_16x16x32_f16(a21, bWc[1], c2, 0, 0, 0);
        if (lc < 8) {
            #pragma unroll
            for (int reg = 0; reg < 4; ++reg)
                sAh2w[(lg*4 + reg)*8 + lc] = f2h(fmaxf(c2[reg], 0.f));
        }
        half8 a3 = {0,0,0,0,0,0,0,0};
        if (l < 16) a3 = *(const half8*)(sAh2w + lc*8);
        f32x4 c3;
        #pragma unroll
        for (int reg = 0; reg < 4; ++reg) c3[reg] = bias3;
        c3 = __builtin_amdgcn_mfma_f32_16x16x32_f16(a3, bW2, c3, 0, 0, 0);
        float gv = sGate[w*4 + rt][g7];
        float lgt[4];
        #pragma unroll
        for (int reg = 0; reg < 4; ++reg) lgt[reg] = c3[reg] * gv;
        float m = fmaxf(fmaxf(lgt[0], lgt[1]), fmaxf(lgt[2], lgt[3]));
        m = fmaxf(m, __shfl_xor(m, 16));
        m = fmaxf(m, __shfl_xor(m, 32));
        float e[4], s = 0.f;
        #pragma unroll
        for (int reg = 0; reg < 4; ++reg) { e[reg] = __expf(lgt[reg] - m); s += e[reg]; }
        s += __shfl_xor(s, 16);
        s += __shfl_xor(s, 32);
        float inv = 1.f / s;
        if (lc < 8) {
            float av[4];
            #pragma unroll
            for (int reg = 0; reg < 4; ++reg) {
                int idv = ids_r[reg];
                float mf = (idv >= 0) ? 1.f : ((idv == -1) ? 0.f : -1.f);
                av[reg] = e[reg] * inv * mf;
            }
            // layout [point][gh=lc][k2=lg*4+reg], stride 24
            unsigned int* d = (unsigned int*)(sAttnB + ((w*4 + rt)*8 + lc)*24 + lg*4);
            d[0] = pack2h(av[0], av[1]);
            d[1] = pack2h(av[2], av[3]);
        }
    }

    // ---- einsum: attn via 2x b128, late v-gather, f16 unpack ----
    {
        int p = lg, kk = lc;
        int n2 = n0 + w*4 + p;
        const unsigned short* ab = sAttnB + ((w*4 + p)*8 + (kk >> 1))*24;
        half8 aa0 = *(const half8*)(ab);
        half8 aa1 = *(const half8*)(ab + 8);
        float4 o = make_float4(0.f, 0.f, 0.f, 0.f);
        #pragma unroll
        for (int k2 = 0; k2 < 16; ++k2) {
            int id2 = max(sIds[w*64 + p*16 + k2], 0);
            float a = (k2 < 8) ? (float)aa0[k2] : (float)aa1[k2-8];
            uint2 u = *(const uint2*)(v_hf + (size_t)id2*64 + kk*4);
            o.x += a * hlo(u.x); o.y += a * hhi(u.x);
            o.z += a * hlo(u.y); o.w += a * hhi(u.y);
        }
        *(float4*)(out + (size_t)n2*64 + kk*4) = o;
    }
}

// ---------------------------------------------------------------------------
extern "C" void kernel_launch(void* const* d_in, const int* in_sizes, int n_in,
                              void* d_out, int out_size, void* d_ws, size_t ws_size,
                              hipStream_t stream)
{
    const float* feat  = (const float*)d_in[0];
    const float* coord = (const float*)d_in[1];
    const int*   ridx  = (const int*)d_in[2];
    const int*   offs  = (const int*)d_in[3];
    const float* Wq = (const float*)d_in[4];  const float* bq = (const float*)d_in[5];  const float* bnq = (const float*)d_in[6];
    const float* Wk = (const float*)d_in[7];  const float* bk = (const float*)d_in[8];  const float* bnk = (const float*)d_in[9];
    const float* Wv = (const float*)d_in[10]; const float* bv = (const float*)d_in[11];
    const float* pe_W1 = (const float*)d_in[12]; const float* pe_b1 = (const float*)d_in[13]; const float* pe_bn = (const float*)d_in[14];
    const float* pe_W2 = (const float*)d_in[15]; const float* pe_b2 = (const float*)d_in[16];
    const float* we_W1 = (const float*)d_in[17]; const float* we_b1 = (const float*)d_in[18]; const float* we_bn = (const float*)d_in[19];
    const float* we_W2 = (const float*)d_in[20]; const float* we_b2 = (const float*)d_in[21];
    const float* cg_W1 = (const float*)d_in[22]; const float* cg_b1 = (const float*)d_in[23]; const float* cg_bn = (const float*)d_in[24];
    const float* cg_W2 = (const float*)d_in[25]; const float* cg_b2 = (const float*)d_in[26];
    float* out = (float*)d_out;
    int N = in_sizes[0] / 64;

    // f16 tables first (16B aligned at ws base)
    unsigned short* v_hf = (unsigned short*)d_ws;               // N*64
    unsigned short* q_hf = v_hf + (size_t)N*64;                 // N*64
    float* kwp   = (float*)(q_hf + (size_t)N*64);               // N*8
    float* qwp   = kwp + (size_t)N*8;                           // N*8
    float* segm  = qwp + (size_t)N*8;                           // 256
    float* peb1f = segm + 256;                                  // 64
    float* cvecg = peb1f + 64;                                  // 8
    float* cgb1f = cvecg + 8;                                   // 64
    float* biasqF= cgb1f + 64;                                  // 64
    float* biaskF= biasqF + 64;                                 // 64
    float* pad0  = biaskF + 64;                                 // 56 pad
    float* cgW1cF= pad0 + 56;                                   // 4096
    unsigned short* WqF     = (unsigned short*)(cgW1cF + 4096); // 4096
    unsigned short* WkF     = WqF + 4096;                       // 4096
    unsigned short* WvF     = WkF + 4096;                       // 4096
    unsigned short* weW1F   = WvF + 4096;                       // 1024
    unsigned short* cgW1aF  = weW1F + 1024;                     // 4096
    unsigned short* cgW1bF  = cgW1aF + 4096;                    // 4096
    unsigned short* cgW2F   = cgW1bF + 4096;                    // 1024
    unsigned short* W1frag  = cgW2F + 1024;                     // 2048
    unsigned short* Wcfrag  = W1frag + 2048;                    // 1024
    unsigned short* W2frag  = Wcfrag + 1024;                    // 512

    k_prep<<<1, 256, 0, stream>>>(pe_W1, pe_b1, pe_bn, pe_W2, pe_b2,
                                  we_W1, we_b1, we_bn, we_W2,
                                  cg_W1, cg_b1, cg_bn, cg_W2,
                                  Wq, bq, bnq, Wk, bk, bnk, Wv,
                                  peb1f, cvecg, cgb1f, biasqF, biaskF, cgW1cF, segm,
                                  WqF, WkF, WvF, weW1F, cgW1aF, cgW1bF, cgW2F,
                                  W1frag, Wcfrag, W2frag);
    k_qkv<<<N/64, 256, 0, stream>>>(feat, offs, WqF, WkF, WvF, weW1F,
                                    biasqF, biaskF, bv,
                                    v_hf, q_hf, kwp, qwp, segm);
    k_main<<<N/16, 256, 0, stream>>>(coord, ridx, v_hf, q_hf, kwp, qwp,
                                     peb1f, cvecg, we_b2, cg_b2,
                                     segm, cgW1cF, cgb1f, offs,
                                     W1frag, Wcfrag, W2frag,
                                     cgW1aF, cgW1bF, cgW2F, out);
}

// Round 17
// 101.092 us; speedup vs baseline: 1.0514x; 1.0514x over previous
//
#include <hip/hip_runtime.h>
#include <hip/hip_bf16.h>
#include <hip/hip_fp16.h>

#define EPSF 1e-5f

typedef __attribute__((ext_vector_type(8))) _Float16 half8;
typedef __attribute__((ext_vector_type(2))) _Float16 half2v;
typedef __attribute__((ext_vector_type(4))) float f32x4;

__device__ __forceinline__ int seg_of(int i, int o0, int o1, int o2) {
    return (i >= o0) + (i >= o1) + (i >= o2);
}

__device__ __forceinline__ unsigned short f2h(float f) {
    _Float16 h = (_Float16)f;
    unsigned short s; __builtin_memcpy(&s, &h, 2);
    return s;
}
// v_cvt_pkrtz_f16_f32: 1 instruction packs two floats to half2
__device__ __forceinline__ unsigned int pack2h(float a, float b) {
    auto h = __builtin_amdgcn_cvt_pkrtz(a, b);   // __fp16 ext_vector(2)
    unsigned int u; __builtin_memcpy(&u, &h, 4);
    return u;
}
__device__ __forceinline__ float hlo(unsigned int u) {
    unsigned short s = (unsigned short)u;
    _Float16 h; __builtin_memcpy(&h, &s, 2);
    return (float)h;
}
__device__ __forceinline__ float hhi(unsigned int u) {
    unsigned short s = (unsigned short)(u >> 16);
    _Float16 h; __builtin_memcpy(&h, &s, 2);
    return (float)h;
}
__device__ __forceinline__ half2v u2h2(unsigned int u) {
    half2v h; __builtin_memcpy(&h, &u, 4);
    return h;
}
__device__ __forceinline__ unsigned int h22u(half2v h) {
    unsigned int u; __builtin_memcpy(&u, &h, 4);
    return u;
}

// stage 16 rows x 64 f16 from global (row-major 64) into LDS (stride 72)
__device__ __forceinline__ void stage_rows_h(const unsigned short* __restrict__ src,
                                             unsigned short* dst, int l) {
    int row = l >> 2, cq = (l & 3) * 16;
    const half8* s = (const half8*)(src + (size_t)row*64 + cq);
    half8* d0 = (half8*)(dst + row*72 + cq);
    d0[0] = s[0];
    d0[1] = s[1];
}

// stage 16 rows x 64 f32 from global into f16 LDS (stride 72)
__device__ __forceinline__ void stage_rows_f32(const float* __restrict__ src,
                                               unsigned short* dst, int l) {
    int row = l >> 2, cq = (l & 3) * 16;
    const float4* s = (const float4*)(src + (size_t)row*64 + cq);
    unsigned int* d = (unsigned int*)(dst + row*72 + cq);
    #pragma unroll
    for (int i = 0; i < 4; ++i) {
        float4 f = s[i];
        d[i*2]   = pack2h(f.x, f.y);
        d[i*2+1] = pack2h(f.z, f.w);
    }
}

// ---------------------------------------------------------------------------
// K0: fold BNs; build all f16 MFMA B-fragments + folded biases; zero seg_max.
// ---------------------------------------------------------------------------
__global__ __launch_bounds__(256) void k_prep(
    const float* __restrict__ pe_W1, const float* __restrict__ pe_b1, const float* __restrict__ pe_bn,
    const float* __restrict__ pe_W2, const float* __restrict__ pe_b2,
    const float* __restrict__ we_W1, const float* __restrict__ we_b1, const float* __restrict__ we_bn,
    const float* __restrict__ we_W2,
    const float* __restrict__ cg_W1, const float* __restrict__ cg_b1, const float* __restrict__ cg_bn,
    const float* __restrict__ cg_W2,
    const float* __restrict__ Wq, const float* __restrict__ bq, const float* __restrict__ bnq,
    const float* __restrict__ Wk, const float* __restrict__ bk, const float* __restrict__ bnk,
    const float* __restrict__ Wv,
    float* __restrict__ peb1f, float* __restrict__ cvecg, float* __restrict__ cgb1f,
    float* __restrict__ biasqF, float* __restrict__ biaskF, float* __restrict__ cgW1cF,
    float* __restrict__ segm,
    unsigned short* __restrict__ WqF, unsigned short* __restrict__ WkF, unsigned short* __restrict__ WvF,
    unsigned short* __restrict__ weW1F, unsigned short* __restrict__ cgW1aF,
    unsigned short* __restrict__ cgW1bF, unsigned short* __restrict__ cgW2F,
    unsigned short* __restrict__ W1frag, unsigned short* __restrict__ Wcfrag,
    unsigned short* __restrict__ W2frag)
{
    int t = threadIdx.x;
    __shared__ float sc1[64], csc[64], sqv[64], skv[64], wsc[8], wsh[8];
    __shared__ float sWe[64][8], sWb[8], sWc[64][8];
    segm[t] = 0.f;
    if (t < 64) {
        float g = pe_bn[t], b = pe_bn[64+t], m = pe_bn[128+t], v = pe_bn[192+t];
        float s = g / sqrtf(v + EPSF);
        sc1[t] = s; peb1f[t] = pe_b1[t]*s + (b - m*s);
        g = cg_bn[t]; b = cg_bn[64+t]; m = cg_bn[128+t]; v = cg_bn[192+t];
        s = g / sqrtf(v + EPSF);
        csc[t] = s; cgb1f[t] = cg_b1[t]*s + (b - m*s);
        g = bnq[t]; b = bnq[64+t]; m = bnq[128+t]; v = bnq[192+t];
        s = g / sqrtf(v + EPSF);
        sqv[t] = s; biasqF[t] = bq[t]*s + (b - m*s);
        g = bnk[t]; b = bnk[64+t]; m = bnk[128+t]; v = bnk[192+t];
        s = g / sqrtf(v + EPSF);
        skv[t] = s; biaskF[t] = bk[t]*s + (b - m*s);
    }
    if (t < 8) {
        float g = we_bn[t], b = we_bn[8+t], m = we_bn[16+t], v = we_bn[24+t];
        float s = g / sqrtf(v + EPSF);
        wsc[t] = s; wsh[t] = b - m*s;
    }
    __syncthreads();
    for (int u = t; u < 512; u += 256) { int g = u & 7; sWe[u >> 3][g] = we_W1[u] * wsc[g]; }
    if (t < 8) sWb[t] = we_b1[t] * wsc[t] + wsh[t];
    __syncthreads();
    for (int u = t; u < 512; u += 256) {
        int h = u >> 3, g = u & 7;
        float a = 0.f;
        for (int c = 0; c < 64; ++c) a += pe_W2[h*64 + c] * sWe[c][g];
        sWc[h][g] = a;
    }
    if (t < 8) {
        float a = sWb[t];
        for (int c = 0; c < 64; ++c) a += pe_b2[c] * sWe[c][t];
        cvecg[t] = a;
    }
    __syncthreads();
    // 64x64 frags (8 tiles x 512)
    for (int u = t; u < 4096; u += 256) {
        int tile = u >> 9, l = (u >> 3) & 63, j = u & 7;
        int col = (tile >> 1)*16 + (l & 15);
        int kk  = (tile & 1)*32 + (l >> 4)*8 + j;
        WqF[u]    = f2h(Wq[kk*64 + col] * sqv[col]);
        WkF[u]    = f2h(Wk[kk*64 + col] * skv[col]);
        WvF[u]    = f2h(Wv[kk*64 + col]);
        cgW1aF[u] = f2h(cg_W1[kk*64 + col] * csc[col]);
        cgW1bF[u] = f2h(cg_W1[(64 + kk)*64 + col] * csc[col]);
    }
    // 64->8/8->8 frags (2 tiles, cols padded to 16)
    for (int u = t; u < 1024; u += 256) {
        int tile = u >> 9, l = (u >> 3) & 63, j = u & 7;
        int col = l & 15;
        int kk  = tile*32 + (l >> 4)*8 + j;
        weW1F[u] = (col < 8) ? f2h(sWe[kk][col]) : 0;
        cgW2F[u] = (col < 8) ? f2h(cg_W2[kk*8 + col]) : 0;
    }
    // cgW1cF: rows 128..191 of cg_W1, BN-folded, f32
    for (int u = t; u < 4096; u += 256) {
        int k = u >> 6, c = u & 63;
        cgW1cF[u] = cg_W1[(128 + k)*64 + c] * csc[c];
    }
    // k_main frags
    {
        int ct = t >> 6, l = t & 63;
        int col = 16*ct + (l & 15), kg = l >> 4;
        #pragma unroll
        for (int j = 0; j < 8; ++j) {
            int k = kg*8 + j;
            float v = (k < 28) ? pe_W1[k*64 + col] * sc1[col] : 0.f;
            W1frag[ct*512 + l*8 + j] = f2h(v);
        }
    }
    if (t < 128) {
        int kg = t >> 6, l = t & 63, g = l & 15;
        #pragma unroll
        for (int j = 0; j < 8; ++j) {
            int k = kg*32 + (l >> 4)*8 + j;
            float v = (g < 8) ? sWc[k][g] : 0.f;
            Wcfrag[kg*512 + l*8 + j] = f2h(v);
        }
    }
    if (t < 64) {
        int l = t, g = l & 15;
        #pragma unroll
        for (int j = 0; j < 8; ++j) {
            float v = (l < 16 && g < 8) ? we_W2[j*8 + g] : 0.f;
            W2frag[l*8 + j] = f2h(v);
        }
    }
}

// ---------------------------------------------------------------------------
// K1: MFMA q/k/v (f16). Block = 4 waves x 16 rows, wave-private LDS.
// ---------------------------------------------------------------------------
__global__ __launch_bounds__(256) void k_qkv(
    const float* __restrict__ feat, const int* __restrict__ offs,
    const unsigned short* __restrict__ WqF, const unsigned short* __restrict__ WkF,
    const unsigned short* __restrict__ WvF, const unsigned short* __restrict__ weW1F,
    const float* __restrict__ biasqF, const float* __restrict__ biaskF,
    const float* __restrict__ bv,
    unsigned short* __restrict__ v_hf, unsigned short* __restrict__ q_hf,
    float* __restrict__ kw, float* __restrict__ qw, float* __restrict__ seg_max)
{
    __shared__ unsigned short sF[4][16*72];
    __shared__ unsigned short sQ[4][16*72];
    __shared__ unsigned short sK[4][16*72];
    __shared__ float sSeg[64];

    int t = threadIdx.x, w = t >> 6, l = t & 63;
    int lc = l & 15, lg = l >> 4;
    int rblk = blockIdx.x * 64;
    int r0 = rblk + w * 16;
    int o0 = offs[0], o1 = offs[1], o2 = offs[2];
    bool fast = seg_of(rblk, o0,o1,o2) == seg_of(rblk + 63, o0,o1,o2);

    if (t < 64) sSeg[t] = 0.f;
    __syncthreads();

    stage_rows_f32(feat + (size_t)r0*64, sF[w], l);
    half8 a0 = *(const half8*)(sF[w] + lc*72 + lg*8);
    half8 a1 = *(const half8*)(sF[w] + lc*72 + 32 + lg*8);

    float bqc[4], bkc[4], bvc[4];
    #pragma unroll
    for (int ct = 0; ct < 4; ++ct) {
        bqc[ct] = biasqF[ct*16 + lc];
        bkc[ct] = biaskF[ct*16 + lc];
        bvc[ct] = bv[ct*16 + lc];
    }

    // ---- q ----
    #pragma unroll
    for (int ct = 0; ct < 4; ++ct) {
        f32x4 z = {0.f,0.f,0.f,0.f};
        half8 b0 = *(const half8*)(WqF + (ct*2+0)*512 + l*8);
        half8 b1 = *(const half8*)(WqF + (ct*2+1)*512 + l*8);
        f32x4 c = __builtin_amdgcn_mfma_f32_16x16x32_f16(a0, b0, z, 0,0,0);
        c = __builtin_amdgcn_mfma_f32_16x16x32_f16(a1, b1, c, 0,0,0);
        float cmax = 0.f;
        #pragma unroll
        for (int reg = 0; reg < 4; ++reg) {
            float qv = fmaxf(c[reg] + bqc[ct], 0.f);
            sQ[w][(lg*4 + reg)*72 + ct*16 + lc] = f2h(qv);
            if (fast) cmax = fmaxf(cmax, qv);
            else atomicMax((unsigned int*)&seg_max[seg_of(r0 + lg*4 + reg,o0,o1,o2)*64 + ct*16 + lc],
                           __float_as_uint(qv));
        }
        if (fast) {
            cmax = fmaxf(cmax, __shfl_xor(cmax, 16));
            cmax = fmaxf(cmax, __shfl_xor(cmax, 32));
            if (lg == 0)
                atomicMax((unsigned int*)&sSeg[ct*16 + lc], __float_as_uint(cmax));
        }
    }
    // ---- seg-max combine early ----
    __syncthreads();
    if (fast && t < 64)
        atomicMax((unsigned int*)&seg_max[seg_of(rblk,o0,o1,o2)*64 + t],
                  __float_as_uint(sSeg[t]));

    // ---- k ----
    #pragma unroll
    for (int ct = 0; ct < 4; ++ct) {
        f32x4 z = {0.f,0.f,0.f,0.f};
        half8 b0 = *(const half8*)(WkF + (ct*2+0)*512 + l*8);
        half8 b1 = *(const half8*)(WkF + (ct*2+1)*512 + l*8);
        f32x4 c = __builtin_amdgcn_mfma_f32_16x16x32_f16(a0, b0, z, 0,0,0);
        c = __builtin_amdgcn_mfma_f32_16x16x32_f16(a1, b1, c, 0,0,0);
        #pragma unroll
        for (int reg = 0; reg < 4; ++reg)
            sK[w][(lg*4 + reg)*72 + ct*16 + lc] = f2h(fmaxf(c[reg] + bkc[ct], 0.f));
    }
    // ---- v (staged f16 into sF, which is dead now) ----
    #pragma unroll
    for (int ct = 0; ct < 4; ++ct) {
        f32x4 z = {0.f,0.f,0.f,0.f};
        half8 b0 = *(const half8*)(WvF + (ct*2+0)*512 + l*8);
        half8 b1 = *(const half8*)(WvF + (ct*2+1)*512 + l*8);
        f32x4 c = __builtin_amdgcn_mfma_f32_16x16x32_f16(a0, b0, z, 0,0,0);
        c = __builtin_amdgcn_mfma_f32_16x16x32_f16(a1, b1, c, 0,0,0);
        #pragma unroll
        for (int reg = 0; reg < 4; ++reg)
            sF[w][(lg*4 + reg)*72 + ct*16 + lc] = f2h(c[reg] + bvc[ct]);
    }
    // ---- kw / qw via MFMA (K=64 -> 8 cols) ----
    {
        half8 wb0 = *(const half8*)(weW1F + l*8);
        half8 wb1 = *(const half8*)(weW1F + 512 + l*8);
        half8 aq0 = *(const half8*)(sQ[w] + lc*72 + lg*8);
        half8 aq1 = *(const half8*)(sQ[w] + lc*72 + 32 + lg*8);
        half8 ak0 = *(const half8*)(sK[w] + lc*72 + lg*8);
        half8 ak1 = *(const half8*)(sK[w] + lc*72 + 32 + lg*8);
        f32x4 z = {0.f,0.f,0.f,0.f};
        f32x4 cq = __builtin_amdgcn_mfma_f32_16x16x32_f16(aq0, wb0, z, 0,0,0);
        cq = __builtin_amdgcn_mfma_f32_16x16x32_f16(aq1, wb1, cq, 0,0,0);
        f32x4 ck = __builtin_amdgcn_mfma_f32_16x16x32_f16(ak0, wb0, z, 0,0,0);
        ck = __builtin_amdgcn_mfma_f32_16x16x32_f16(ak1, wb1, ck, 0,0,0);
        if (lc < 8) {
            #pragma unroll
            for (int reg = 0; reg < 4; ++reg) {
                qw[(size_t)(r0 + lg*4 + reg)*8 + lc] = cq[reg];
                kw[(size_t)(r0 + lg*4 + reg)*8 + lc] = ck[reg];
            }
        }
    }
    // ---- q_hf / v_hf global writes ----
    #pragma unroll
    for (int rep = 0; rep < 2; ++rep) {
        int row = (l >> 3) + rep*8;
        int ch = (l & 7) * 8;
        half8 vq = *(const half8*)(sQ[w] + row*72 + ch);
        *(half8*)(q_hf + (size_t)(r0 + row)*64 + ch) = vq;
        half8 vv = *(const half8*)(sF[w] + row*72 + ch);
        *(half8*)(v_hf + (size_t)(r0 + row)*64 + ch) = vv;
    }
}

// ---------------------------------------------------------------------------
// K_seg: gseg2[s][c] = cgb1f[c] + seg_max[s] @ cgW1cF. 1 block (computed ONCE,
// not per k_main block: avoids 268 MB of per-block L2 re-reads).
// ---------------------------------------------------------------------------
__global__ __launch_bounds__(256) void k_seg(
    const float* __restrict__ seg_max, const float* __restrict__ cgW1cF,
    const float* __restrict__ cgb1f, float* __restrict__ gseg2)
{
    int t = threadIdx.x;
    int c = t & 63, s = t >> 6;
    float a = cgb1f[c];
    for (int j = 0; j < 64; ++j) a += seg_max[s*64 + j] * cgW1cF[j*64 + c];
    gseg2[s*64 + c] = a;
}

// ---------------------------------------------------------------------------
// K3 (fused): gate (phase A) + PE/softmax/einsum (phase B).
// R10 structure (xe once into block-wide sA1; gseg2 from global) + f16.
// LDS 38.4 KB -> 4 blocks/CU.
// ---------------------------------------------------------------------------
__global__ __launch_bounds__(256, 4) void k_main(
    const float* __restrict__ coord, const int* __restrict__ ridx,
    const unsigned short* __restrict__ v_hf, const unsigned short* __restrict__ q_hf,
    const float* __restrict__ kw, const float* __restrict__ qw,
    const float* __restrict__ peb1f, const float* __restrict__ cvecg,
    const float* __restrict__ we_b2, const float* __restrict__ cg_b2,
    const float* __restrict__ gseg2, const int* __restrict__ offs,
    const unsigned short* __restrict__ W1frag, const unsigned short* __restrict__ Wcfrag,
    const unsigned short* __restrict__ W2frag,
    const unsigned short* __restrict__ cgW1aF, const unsigned short* __restrict__ cgW1bF,
    const unsigned short* __restrict__ cgW2F,
    float* __restrict__ out)
{
    __shared__ __align__(16) unsigned short sA1[256*40];   // 20480 B xe rows (block-wide)
    __shared__ __align__(16) unsigned short sA2[4][16*72]; // 9216 B per-wave H1
    __shared__ __align__(16) unsigned short sU[3584];      // 7168 B union
    __shared__ float sGate[16][9];                         // 576 B
    __shared__ int sIds[256];                              // 1024 B

    int t = threadIdx.x, w = t >> 6, l = t & 63;
    int lc = l & 15, lg = l >> 4;
    int n0 = blockIdx.x * 16;
    int o0 = offs[0], o1 = offs[1], o2 = offs[2];

    unsigned short* sQg = sU;
    unsigned short* sN  = sU + 1152;
    unsigned short* sHg = sU + 2304;
    unsigned short* sAh2w  = sU + w*128;
    unsigned short* sAttnB = sU + 512;

    // ---- step 1: ids + xe row computed ONCE (pkrtz packing) ----
    int id = ridx[(size_t)n0*16 + t];
    sIds[t] = id;
    int ids = max(id, 0);
    int nself = n0 + (t >> 4);
    {
        float cx = coord[nself*3], cy = coord[nself*3+1], cz = coord[nself*3+2];
        float dx = coord[ids*3]   - cx;
        float dy = coord[ids*3+1] - cy;
        float dz = coord[ids*3+2] - cz;
        float dist = sqrtf(dx*dx + dy*dy + dz*dz);
        unsigned int* row = (unsigned int*)sA1 + t*20;
        row[0] = pack2h(dx, dy);
        row[1] = pack2h(dz, dist);
        float sx, cx2, sy, cy2, sz, cz2;
        __sincosf(dx * 3.14159265358979f, &sx, &cx2);
        __sincosf(dy * 3.14159265358979f, &sy, &cy2);
        __sincosf(dz * 3.14159265358979f, &sz, &cz2);
        row[2]  = pack2h(sx, sy);
        row[3]  = pack2h(cx2, cy2);
        row[10] = pack2h(sz, cz2);
        #pragma unroll
        for (int fi = 1; fi < 4; ++fi) {
            float nsx = 2.f*sx*cx2, ncx = fmaf(-2.f*sx, sx, 1.f);
            float nsy = 2.f*sy*cy2, ncy = fmaf(-2.f*sy, sy, 1.f);
            float nsz = 2.f*sz*cz2, ncz = fmaf(-2.f*sz, sz, 1.f);
            row[2 + 2*fi] = pack2h(nsx, nsy);
            row[3 + 2*fi] = pack2h(ncx, ncy);
            row[10 + fi]  = pack2h(nsz, ncz);
            sx = nsx; cx2 = ncx; sy = nsy; cy2 = ncy; sz = nsz; cz2 = ncz;
        }
        row[14] = 0u; row[15] = 0u;
    }
    if (t < 64) stage_rows_h(q_hf + (size_t)n0*64, sQg, t);
    __syncthreads();   // sIds + sQg + sA1 ready

    // ---- step 2: neighbor-max gather in packed f16 (v_pk_max_f16) ----
    {
        int p = t >> 4, s = t & 15;
        const int* ip = &sIds[p*16];
        half2v m0 = (half2v)0, m1 = (half2v)0;
        #pragma unroll
        for (int kb = 0; kb < 16; kb += 4) {
            uint2 u[4];
            #pragma unroll
            for (int j = 0; j < 4; ++j) {
                int idn = max(ip[kb + j], 0);
                u[j] = *(const uint2*)(q_hf + (size_t)idn*64 + s*4);
            }
            #pragma unroll
            for (int j = 0; j < 4; ++j) {
                m0 = __builtin_elementwise_max(m0, u2h2(u[j].x));
                m1 = __builtin_elementwise_max(m1, u2h2(u[j].y));
            }
        }
        unsigned int* d = (unsigned int*)(sN + p*72 + s*4);
        d[0] = h22u(m0);
        d[1] = h22u(m1);
    }
    __syncthreads();   // sN ready

    // ---- step 3: gate H1 (wave w owns output col-tile ct=w) ----
    {
        half8 a0 = *(const half8*)(sQg + lc*72 + lg*8);
        half8 a1 = *(const half8*)(sQg + lc*72 + 32 + lg*8);
        half8 nv0 = *(const half8*)(sN + lc*72 + lg*8);
        half8 nv1 = *(const half8*)(sN + lc*72 + 32 + lg*8);
        f32x4 c4;
        #pragma unroll
        for (int reg = 0; reg < 4; ++reg)
            c4[reg] = gseg2[seg_of(n0 + lg*4 + reg, o0, o1, o2)*64 + w*16 + lc];
        half8 b0 = *(const half8*)(cgW1aF + (w*2+0)*512 + l*8);
        half8 b1 = *(const half8*)(cgW1aF + (w*2+1)*512 + l*8);
        c4 = __builtin_amdgcn_mfma_f32_16x16x32_f16(a0, b0, c4, 0,0,0);
        c4 = __builtin_amdgcn_mfma_f32_16x16x32_f16(a1, b1, c4, 0,0,0);
        half8 b2 = *(const half8*)(cgW1bF + (w*2+0)*512 + l*8);
        half8 b3 = *(const half8*)(cgW1bF + (w*2+1)*512 + l*8);
        c4 = __builtin_amdgcn_mfma_f32_16x16x32_f16(nv0, b2, c4, 0,0,0);
        c4 = __builtin_amdgcn_mfma_f32_16x16x32_f16(nv1, b3, c4, 0,0,0);
        #pragma unroll
        for (int reg = 0; reg < 4; ++reg)
            sHg[(lg*4 + reg)*72 + w*16 + lc] = f2h(fmaxf(c4[reg], 0.f));
    }
    __syncthreads();   // sHg ready

    // ---- step 4: final gate MFMA (wave 0 only) ----
    if (w == 0) {
        half8 ah0 = *(const half8*)(sHg + lc*72 + lg*8);
        half8 ah1 = *(const half8*)(sHg + lc*72 + 32 + lg*8);
        half8 w0f = *(const half8*)(cgW2F + l*8);
        half8 w1f = *(const half8*)(cgW2F + 512 + l*8);
        float bg = cg_b2[lc & 7];
        f32x4 cg;
        #pragma unroll
        for (int reg = 0; reg < 4; ++reg) cg[reg] = bg;
        cg = __builtin_amdgcn_mfma_f32_16x16x32_f16(ah0, w0f, cg, 0,0,0);
        cg = __builtin_amdgcn_mfma_f32_16x16x32_f16(ah1, w1f, cg, 0,0,0);
        if (lc < 8) {
            #pragma unroll
            for (int reg = 0; reg < 4; ++reg)
                sGate[lg*4 + reg][lc] = 1.f / (1.f + __expf(-cg[reg]));
        }
    }
    __syncthreads();   // sGate ready; phase-A scratch dead -> reuse

    // ---- phase B: per-wave PE pipeline ----
    int g7 = lc & 7;
    half8 bW1[4], bWc[2], bW2;
    #pragma unroll
    for (int ct = 0; ct < 4; ++ct) bW1[ct] = *(const half8*)(W1frag + ct*512 + l*8);
    bWc[0] = *(const half8*)(Wcfrag + l*8);
    bWc[1] = *(const half8*)(Wcfrag + 512 + l*8);
    bW2 = *(const half8*)(W2frag + l*8);

    float bias1[4];
    #pragma unroll
    for (int ct = 0; ct < 4; ++ct) bias1[ct] = peb1f[16*ct + lc];
    float cvec_g = cvecg[g7];
    float bias3 = we_b2[g7];

    #pragma unroll
    for (int rt = 0; rt < 4; ++rt) {
        int n = n0 + w*4 + rt;
        half8 a1 = *(const half8*)(sA1 + (w*64 + rt*16 + lc)*40 + lg*8);
        f32x4 c1[4];
        #pragma unroll
        for (int ct = 0; ct < 4; ++ct) {
            f32x4 z = {0.f, 0.f, 0.f, 0.f};
            c1[ct] = __builtin_amdgcn_mfma_f32_16x16x32_f16(a1, bW1[ct], z, 0, 0, 0);
        }
        #pragma unroll
        for (int ct = 0; ct < 4; ++ct) {
            #pragma unroll
            for (int reg = 0; reg < 4; ++reg) {
                float h1 = fmaxf(c1[ct][reg] + bias1[ct], 0.f);
                sA2[w][(lg*4 + reg)*72 + 16*ct + lc] = f2h(h1);
            }
        }
        int ids_r[4];
        #pragma unroll
        for (int reg = 0; reg < 4; ++reg) ids_r[reg] = sIds[w*64 + rt*16 + lg*4 + reg];
        float qwv = qw[(size_t)n*8 + g7];
        f32x4 c2;
        #pragma unroll
        for (int reg = 0; reg < 4; ++reg)
            c2[reg] = kw[(size_t)max(ids_r[reg],0)*8 + g7] - qwv + cvec_g;
        half8 a20 = *(const half8*)(sA2[w] + lc*72 + lg*8);
        half8 a21 = *(const half8*)(sA2[w] + lc*72 + 32 + lg*8);
        c2 = __builtin_amdgcn_mfma_f32_16x16x32_f16(a20, bWc[0], c2, 0, 0, 0);
        c2 = __builtin_amdgcn_mfma_f32_16x16x32_f16(a21, bWc[1], c2, 0, 0, 0);
        if (lc < 8) {
            #pragma unroll
            for (int reg = 0; reg < 4; ++reg)
                sAh2w[(lg*4 + reg)*8 + lc] = f2h(fmaxf(c2[reg], 0.f));
        }
        half8 a3 = {0,0,0,0,0,0,0,0};
        if (l < 16) a3 = *(const half8*)(sAh2w + lc*8);
        f32x4 c3;
        #pragma unroll
        for (int reg = 0; reg < 4; ++reg) c3[reg] = bias3;
        c3 = __builtin_amdgcn_mfma_f32_16x16x32_f16(a3, bW2, c3, 0, 0, 0);
        float gv = sGate[w*4 + rt][g7];
        float lgt[4];
        #pragma unroll
        for (int reg = 0; reg < 4; ++reg) lgt[reg] = c3[reg] * gv;
        float m = fmaxf(fmaxf(lgt[0], lgt[1]), fmaxf(lgt[2], lgt[3]));
        m = fmaxf(m, __shfl_xor(m, 16));
        m = fmaxf(m, __shfl_xor(m, 32));
        float e[4], s = 0.f;
        #pragma unroll
        for (int reg = 0; reg < 4; ++reg) { e[reg] = __expf(lgt[reg] - m); s += e[reg]; }
        s += __shfl_xor(s, 16);
        s += __shfl_xor(s, 32);
        float inv = 1.f / s;
        if (lc < 8) {
            float av[4];
            #pragma unroll
            for (int reg = 0; reg < 4; ++reg) {
                int idv = ids_r[reg];
                float mf = (idv >= 0) ? 1.f : ((idv == -1) ? 0.f : -1.f);
                av[reg] = e[reg] * inv * mf;
            }
            // layout [point][gh=lc][k2=lg*4+reg], stride 24
            unsigned int* d = (unsigned int*)(sAttnB + ((w*4 + rt)*8 + lc)*24 + lg*4);
            d[0] = pack2h(av[0], av[1]);
            d[1] = pack2h(av[2], av[3]);
        }
    }

    // ---- einsum: attn via 2x b128, late v-gather, f16 unpack ----
    {
        int p = lg, kk = lc;
        int n2 = n0 + w*4 + p;
        const unsigned short* ab = sAttnB + ((w*4 + p)*8 + (kk >> 1))*24;
        half8 aa0 = *(const half8*)(ab);
        half8 aa1 = *(const half8*)(ab + 8);
        float4 o = make_float4(0.f, 0.f, 0.f, 0.f);
        #pragma unroll
        for (int k2 = 0; k2 < 16; ++k2) {
            int id2 = max(sIds[w*64 + p*16 + k2], 0);
            float a = (k2 < 8) ? (float)aa0[k2] : (float)aa1[k2-8];
            uint2 u = *(const uint2*)(v_hf + (size_t)id2*64 + kk*4);
            o.x += a * hlo(u.x); o.y += a * hhi(u.x);
            o.z += a * hlo(u.y); o.w += a * hhi(u.y);
        }
        *(float4*)(out + (size_t)n2*64 + kk*4) = o;
    }
}

// ---------------------------------------------------------------------------
extern "C" void kernel_launch(void* const* d_in, const int* in_sizes, int n_in,
                              void* d_out, int out_size, void* d_ws, size_t ws_size,
                              hipStream_t stream)
{
    const float* feat  = (const float*)d_in[0];
    const float* coord = (const float*)d_in[1];
    const int*   ridx  = (const int*)d_in[2];
    const int*   offs  = (const int*)d_in[3];
    const float* Wq = (const float*)d_in[4];  const float* bq = (const float*)d_in[5];  const float* bnq = (const float*)d_in[6];
    const float* Wk = (const float*)d_in[7];  const float* bk = (const float*)d_in[8];  const float* bnk = (const float*)d_in[9];
    const float* Wv = (const float*)d_in[10]; const float* bv = (const float*)d_in[11];
    const float* pe_W1 = (const float*)d_in[12]; const float* pe_b1 = (const float*)d_in[13]; const float* pe_bn = (const float*)d_in[14];
    const float* pe_W2 = (const float*)d_in[15]; const float* pe_b2 = (const float*)d_in[16];
    const float* we_W1 = (const float*)d_in[17]; const float* we_b1 = (const float*)d_in[18]; const float* we_bn = (const float*)d_in[19];
    const float* we_W2 = (const float*)d_in[20]; const float* we_b2 = (const float*)d_in[21];
    const float* cg_W1 = (const float*)d_in[22]; const float* cg_b1 = (const float*)d_in[23]; const float* cg_bn = (const float*)d_in[24];
    const float* cg_W2 = (const float*)d_in[25]; const float* cg_b2 = (const float*)d_in[26];
    float* out = (float*)d_out;
    int N = in_sizes[0] / 64;

    // f16 tables first (16B aligned at ws base)
    unsigned short* v_hf = (unsigned short*)d_ws;               // N*64
    unsigned short* q_hf = v_hf + (size_t)N*64;                 // N*64
    float* kwp   = (float*)(q_hf + (size_t)N*64);               // N*8
    float* qwp   = kwp + (size_t)N*8;                           // N*8
    float* segm  = qwp + (size_t)N*8;                           // 256
    float* gseg2 = segm + 256;                                  // 256
    float* peb1f = gseg2 + 256;                                 // 64
    float* cvecg = peb1f + 64;                                  // 8
    float* cgb1f = cvecg + 8;                                   // 64
    float* biasqF= cgb1f + 64;                                  // 64
    float* biaskF= biasqF + 64;                                 // 64
    float* pad0  = biaskF + 64;                                 // 56 pad
    float* cgW1cF= pad0 + 56;                                   // 4096
    unsigned short* WqF     = (unsigned short*)(cgW1cF + 4096); // 4096
    unsigned short* WkF     = WqF + 4096;                       // 4096
    unsigned short* WvF     = WkF + 4096;                       // 4096
    unsigned short* weW1F   = WvF + 4096;                       // 1024
    unsigned short* cgW1aF  = weW1F + 1024;                     // 4096
    unsigned short* cgW1bF  = cgW1aF + 4096;                    // 4096
    unsigned short* cgW2F   = cgW1bF + 4096;                    // 1024
    unsigned short* W1frag  = cgW2F + 1024;                     // 2048
    unsigned short* Wcfrag  = W1frag + 2048;                    // 1024
    unsigned short* W2frag  = Wcfrag + 1024;                    // 512

    k_prep<<<1, 256, 0, stream>>>(pe_W1, pe_b1, pe_bn, pe_W2, pe_b2,
                                  we_W1, we_b1, we_bn, we_W2,
                                  cg_W1, cg_b1, cg_bn, cg_W2,
                                  Wq, bq, bnq, Wk, bk, bnk, Wv,
                                  peb1f, cvecg, cgb1f, biasqF, biaskF, cgW1cF, segm,
                                  WqF, WkF, WvF, weW1F, cgW1aF, cgW1bF, cgW2F,
                                  W1frag, Wcfrag, W2frag);
    k_qkv<<<N/64, 256, 0, stream>>>(feat, offs, WqF, WkF, WvF, weW1F,
                                    biasqF, biaskF, bv,
                                    v_hf, q_hf, kwp, qwp, segm);
    k_seg<<<1, 256, 0, stream>>>(segm, cgW1cF, cgb1f, gseg2);
    k_main<<<N/16, 256, 0, stream>>>(coord, ridx, v_hf, q_hf, kwp, qwp,
                                     peb1f, cvecg, we_b2, cg_b2,
                                     gseg2, offs,
                                     W1frag, Wcfrag, W2frag,
                                     cgW1aF, cgW1bF, cgW2F, out);
}